// Round 4
// baseline (127.296 us; speedup 1.0000x reference)
//
#include <hip/hip_runtime.h>

#define BB   256
#define NIN  1152
#define OO   10
#define IL   8
#define OL   16
#define ROW  (OO*OL)      // 160
#define EPSQ 1e-7f
#define NCH  144
#define NPER 8            // NIN/NCH

typedef unsigned short ushx8 __attribute__((ext_vector_type(8)));
typedef unsigned short ushx4 __attribute__((ext_vector_type(4)));

__device__ __forceinline__ unsigned short f2bf(float f) {
    unsigned u = __builtin_bit_cast(unsigned, f);
    u += 0x7FFFu + ((u >> 16) & 1u);   // RNE
    return (unsigned short)(u >> 16);
}
__device__ __forceinline__ float bf2f(unsigned short h) {
    unsigned u = ((unsigned)h) << 16;
    return __builtin_bit_cast(float, u);
}

// K2: build u_hat[b][n][o*16+k] in bf16.
// Grid (NIN/2, BB/32); block 320 = 2 n-groups x 160 (o,k) lanes, 32 b's each.
// w coeffs in registers (re-read 8x total, L2-resident); x read once.
__global__ __launch_bounds__(320) void caps_build(
    const float* __restrict__ x, const float* __restrict__ w,
    unsigned short* __restrict__ u)
{
    const int t  = threadIdx.x;
    const int nn = t / ROW;            // 0..1
    const int tt = t - nn * ROW;       // 0..159 = o*16+k
    const int o  = tt >> 4;
    const int k  = tt & 15;
    const int n  = blockIdx.x * 2 + nn;
    const int b0 = blockIdx.y * 32;

    float wr[IL];
    #pragma unroll
    for (int i = 0; i < IL; ++i)
        wr[i] = w[(size_t)n * (OO * IL * OL) + (o * IL + i) * OL + k];

    unsigned short* up = u + ((size_t)b0 * NIN + n) * ROW + tt;
    const float4* xb = reinterpret_cast<const float4*>(x + ((size_t)b0 * NIN + n) * IL);

    #pragma unroll 4
    for (int bl = 0; bl < 32; ++bl) {
        const float4 xa = xb[(size_t)bl * (NIN * 2)];
        const float4 xc = xb[(size_t)bl * (NIN * 2) + 1];
        float s;
        s = wr[0] * xa.x;
        s = fmaf(wr[1], xa.y, s);
        s = fmaf(wr[2], xa.z, s);
        s = fmaf(wr[3], xa.w, s);
        s = fmaf(wr[4], xc.x, s);
        s = fmaf(wr[5], xc.y, s);
        s = fmaf(wr[6], xc.z, s);
        s = fmaf(wr[7], xc.w, s);
        up[(size_t)bl * ((size_t)NIN * ROW)] = f2bf(s);
    }
}

// K3: iter0 — s0[b,o,k] = 0.1*sum_n u + bias, squash -> v0. Grid: Bc blocks.
__global__ __launch_bounds__(256) void caps_iter0(
    const unsigned short* __restrict__ u, const float* __restrict__ bias,
    float* __restrict__ v0)
{
    __shared__ float red[12][ROW];
    const int t = threadIdx.x;
    const int bl = blockIdx.x;
    if (t < 240) {
        const int c = t % 20;   // 16B chunk within the 320B row
        const int j = t / 20;   // n-lane 0..11
        const ushx8* base = reinterpret_cast<const ushx8*>(u + (size_t)bl * NIN * ROW);
        float acc[8] = {0.f,0.f,0.f,0.f,0.f,0.f,0.f,0.f};
        for (int m = 0; m < 96; m += 4) {
            const size_t n0 = (size_t)(j + 12 * m);
            ushx8 a0 = base[(n0)      * 20 + c];
            ushx8 a1 = base[(n0 + 12) * 20 + c];
            ushx8 a2 = base[(n0 + 24) * 20 + c];
            ushx8 a3 = base[(n0 + 36) * 20 + c];
            #pragma unroll
            for (int e = 0; e < 8; ++e)
                acc[e] += (bf2f(a0[e]) + bf2f(a1[e])) + (bf2f(a2[e]) + bf2f(a3[e]));
        }
        #pragma unroll
        for (int e = 0; e < 8; ++e) red[j][c * 8 + e] = acc[e];
    }
    __syncthreads();
    if (t < ROW) {
        float s = 0.f;
        #pragma unroll
        for (int j = 0; j < 12; ++j) s += red[j][t];
        s = s * 0.1f + bias[t];
        float d = s * s;
        d += __shfl_xor(d, 1, 16);
        d += __shfl_xor(d, 2, 16);
        d += __shfl_xor(d, 4, 16);
        d += __shfl_xor(d, 8, 16);
        const float f = d / ((1.f + d) * sqrtf(d + EPSQ));
        v0[(size_t)bl * ROW + t] = f * s;
    }
}

// K4: one routing iteration over materialized u_hat. 4 lanes per b (k-quads),
// 64 b per 256-thread block. Grid (Bc/64, NCH).
__global__ __launch_bounds__(256) void caps_iter(
    const unsigned short* __restrict__ u, const float* __restrict__ vsum,
    float* __restrict__ partial)
{
    const int t = threadIdx.x;
    const int q = t & 3;
    const int g = t >> 2;
    const int bl = blockIdx.x * (blockDim.x >> 2) + g;
    const int chunk = blockIdx.y;

    float4 vs[OO];
    #pragma unroll
    for (int o = 0; o < OO; ++o)
        vs[o] = *reinterpret_cast<const float4*>(vsum + (size_t)bl * ROW + o * OL + q * 4);

    float4 sp[OO];
    #pragma unroll
    for (int o = 0; o < OO; ++o) sp[o] = make_float4(0.f, 0.f, 0.f, 0.f);

    const unsigned short* ub = u + ((size_t)bl * NIN + (size_t)chunk * NPER) * ROW;
    for (int nn = 0; nn < NPER; ++nn) {
        const unsigned short* un = ub + (size_t)nn * ROW;
        ushx4 raw[OO];
        #pragma unroll
        for (int o = 0; o < OO; ++o)
            raw[o] = *reinterpret_cast<const ushx4*>(un + o * OL + q * 4);

        float bij[OO];
        #pragma unroll
        for (int o = 0; o < OO; ++o) {
            float d = bf2f(raw[o][0]) * vs[o].x;
            d = fmaf(bf2f(raw[o][1]), vs[o].y, d);
            d = fmaf(bf2f(raw[o][2]), vs[o].z, d);
            d = fmaf(bf2f(raw[o][3]), vs[o].w, d);
            d += __shfl_xor(d, 1, 4);
            d += __shfl_xor(d, 2, 4);
            bij[o] = d;
        }
        float m = bij[0];
        #pragma unroll
        for (int o = 1; o < OO; ++o) m = fmaxf(m, bij[o]);
        float e[OO], se = 0.f;
        #pragma unroll
        for (int o = 0; o < OO; ++o) { e[o] = __expf(bij[o] - m); se += e[o]; }
        const float r = 1.f / se;
        #pragma unroll
        for (int o = 0; o < OO; ++o) {
            const float c = e[o] * r;
            sp[o].x = fmaf(c, bf2f(raw[o][0]), sp[o].x);
            sp[o].y = fmaf(c, bf2f(raw[o][1]), sp[o].y);
            sp[o].z = fmaf(c, bf2f(raw[o][2]), sp[o].z);
            sp[o].w = fmaf(c, bf2f(raw[o][3]), sp[o].w);
        }
    }
    float* pp = partial + ((size_t)bl * NCH + chunk) * ROW + q * 4;
    #pragma unroll
    for (int o = 0; o < OO; ++o)
        *reinterpret_cast<float4*>(pp + o * OL) = sp[o];
}

// K5: sum partials over chunks + bias, squash; optional prevAdd (v running sum).
__global__ __launch_bounds__(192) void caps_reduce_squash(
    const float* __restrict__ partial, const float* __restrict__ bias,
    const float* __restrict__ prevAdd, float* __restrict__ out)
{
    const int t = threadIdx.x;
    if (t >= ROW) return;
    const int bl = blockIdx.x;

    float s0 = bias[t], s1 = 0.f, s2 = 0.f, s3 = 0.f;
    const float* p = partial + (size_t)bl * NCH * ROW + t;
    for (int ch = 0; ch < NCH; ch += 4) {
        s0 += p[(size_t)(ch + 0) * ROW];
        s1 += p[(size_t)(ch + 1) * ROW];
        s2 += p[(size_t)(ch + 2) * ROW];
        s3 += p[(size_t)(ch + 3) * ROW];
    }
    float s = (s0 + s1) + (s2 + s3);

    float d = s * s;
    d += __shfl_xor(d, 1, 16);
    d += __shfl_xor(d, 2, 16);
    d += __shfl_xor(d, 4, 16);
    d += __shfl_xor(d, 8, 16);
    const float f = d / ((1.f + d) * sqrtf(d + EPSQ));
    float v = f * s;
    if (prevAdd) v += prevAdd[(size_t)bl * ROW + t];
    out[(size_t)bl * ROW + t] = v;
}

extern "C" void kernel_launch(void* const* d_in, const int* in_sizes, int n_in,
                              void* d_out, int out_size, void* d_ws, size_t ws_size,
                              hipStream_t stream) {
    const float* x    = (const float*)d_in[0]; // (B, NIN, 8, 1)
    const float* w    = (const float*)d_in[1]; // (1, NIN, O, 8, 16)
    const float* bias = (const float*)d_in[2]; // (1, 1, O, 16, 1)
    float* out = (float*)d_out;                // (B, 1, O, 16, 1)

    unsigned short* u  = (unsigned short*)d_ws;                      // BB*NIN*ROW bf16
    float* partial = (float*)((char*)d_ws + (size_t)BB * NIN * ROW * 2);
    float* v0  = partial + (size_t)BB * NCH * ROW;
    float* vsb = v0 + (size_t)BB * ROW;

    const dim3 bgrid(NIN / 2, BB / 32);
    const dim3 g4(BB / 64, NCH);

    caps_build<<<bgrid, 320, 0, stream>>>(x, w, u);
    caps_iter0<<<BB, 256, 0, stream>>>(u, bias, v0);
    caps_iter<<<g4, 256, 0, stream>>>(u, v0, partial);
    caps_reduce_squash<<<BB, 192, 0, stream>>>(partial, bias, v0, vsb);
    caps_iter<<<g4, 256, 0, stream>>>(u, vsb, partial);
    caps_reduce_squash<<<BB, 192, 0, stream>>>(partial, bias, nullptr, out);
}

// Round 5
// 102.738 us; speedup vs baseline: 1.2390x; 1.2390x over previous
//
#include <hip/hip_runtime.h>
#include <hip/hip_bf16.h>

#define BB   256
#define NIN  1152
#define OO   10
#define IL   8
#define OL   16
#define ROW  (OO*OL)      // 160
#define EPSQ 1e-7f
#define NCH  144
#define NPER 8            // NIN/NCH

typedef unsigned short ushx8 __attribute__((ext_vector_type(8)));
typedef unsigned short ushx4 __attribute__((ext_vector_type(4)));

__device__ __forceinline__ float bf2f(unsigned short h) {
    unsigned u = ((unsigned)h) << 16;
    return __builtin_bit_cast(float, u);
}

// K2: build u_hat[b][n][o*16+k] in bf16, 16B stores.
// Block 320 = 16 n-groups x 20 lanes; lane = (o, k-octet), owns 8 k's.
// Grid (NIN/16, BB/8); each thread loops 8 b's with w in registers.
__global__ __launch_bounds__(320) void caps_build(
    const float* __restrict__ x, const float* __restrict__ w,
    unsigned short* __restrict__ u)
{
    const int t  = threadIdx.x;
    const int nl = t / 20;             // 0..15
    const int s  = t - nl * 20;        // 0..19
    const int o  = s >> 1;
    const int k8 = s & 1;
    const int n  = blockIdx.x * 16 + nl;
    const int b0 = blockIdx.y * 8;

    // w[n, o, i, k8*8 .. +7], i = 0..7 -> 64 register-resident coeffs
    const float* wb = w + (size_t)n * (OO * IL * OL) + (o * IL) * OL + k8 * 8;
    float wr[IL][8];
    #pragma unroll
    for (int i = 0; i < IL; ++i) {
        const float4 wa = *reinterpret_cast<const float4*>(wb + i * OL);
        const float4 wc = *reinterpret_cast<const float4*>(wb + i * OL + 4);
        wr[i][0] = wa.x; wr[i][1] = wa.y; wr[i][2] = wa.z; wr[i][3] = wa.w;
        wr[i][4] = wc.x; wr[i][5] = wc.y; wr[i][6] = wc.z; wr[i][7] = wc.w;
    }

    const float4* xb = reinterpret_cast<const float4*>(x + ((size_t)b0 * NIN + n) * IL);
    unsigned short* ub = u + ((size_t)b0 * NIN + n) * ROW + o * OL + k8 * 8;

    #pragma unroll 4
    for (int bl = 0; bl < 8; ++bl) {
        const float4 xa = xb[(size_t)bl * (NIN * 2)];
        const float4 xc = xb[(size_t)bl * (NIN * 2) + 1];
        const float xv[IL] = {xa.x, xa.y, xa.z, xa.w, xc.x, xc.y, xc.z, xc.w};

        float uv[8];
        #pragma unroll
        for (int j = 0; j < 8; ++j) {
            float acc = wr[0][j] * xv[0];
            #pragma unroll
            for (int i = 1; i < IL; ++i) acc = fmaf(wr[i][j], xv[i], acc);
            uv[j] = acc;
        }

        union { ushx8 v; __hip_bfloat162 h[4]; } pk;
        #pragma unroll
        for (int j = 0; j < 4; ++j)
            pk.h[j] = __float22bfloat162_rn(make_float2(uv[2 * j], uv[2 * j + 1]));
        *reinterpret_cast<ushx8*>(ub + (size_t)bl * ((size_t)NIN * ROW)) = pk.v;
    }
}

// K3: iter0 — s0[b,o,k] = 0.1*sum_n u + bias, squash -> v0. Grid: BB blocks.
__global__ __launch_bounds__(256) void caps_iter0(
    const unsigned short* __restrict__ u, const float* __restrict__ bias,
    float* __restrict__ v0)
{
    __shared__ float red[12][ROW];
    const int t = threadIdx.x;
    const int bl = blockIdx.x;
    if (t < 240) {
        const int c = t % 20;   // 16B chunk within the 320B row
        const int j = t / 20;   // n-lane 0..11
        const ushx8* base = reinterpret_cast<const ushx8*>(u + (size_t)bl * NIN * ROW);
        float acc[8] = {0.f,0.f,0.f,0.f,0.f,0.f,0.f,0.f};
        for (int m = 0; m < 96; m += 4) {
            const size_t n0 = (size_t)(j + 12 * m);
            ushx8 a0 = base[(n0)      * 20 + c];
            ushx8 a1 = base[(n0 + 12) * 20 + c];
            ushx8 a2 = base[(n0 + 24) * 20 + c];
            ushx8 a3 = base[(n0 + 36) * 20 + c];
            #pragma unroll
            for (int e = 0; e < 8; ++e)
                acc[e] += (bf2f(a0[e]) + bf2f(a1[e])) + (bf2f(a2[e]) + bf2f(a3[e]));
        }
        #pragma unroll
        for (int e = 0; e < 8; ++e) red[j][c * 8 + e] = acc[e];
    }
    __syncthreads();
    if (t < ROW) {
        float s = 0.f;
        #pragma unroll
        for (int j = 0; j < 12; ++j) s += red[j][t];
        s = s * 0.1f + bias[t];
        float d = s * s;
        d += __shfl_xor(d, 1, 16);
        d += __shfl_xor(d, 2, 16);
        d += __shfl_xor(d, 4, 16);
        d += __shfl_xor(d, 8, 16);
        const float f = d / ((1.f + d) * sqrtf(d + EPSQ));
        v0[(size_t)bl * ROW + t] = f * s;
    }
}

// K4: one routing iteration over materialized u_hat. 4 lanes per b (k-quads),
// 64 b per 256-thread block. Grid (BB/64, NCH).
__global__ __launch_bounds__(256) void caps_iter(
    const unsigned short* __restrict__ u, const float* __restrict__ vsum,
    float* __restrict__ partial)
{
    const int t = threadIdx.x;
    const int q = t & 3;
    const int g = t >> 2;
    const int bl = blockIdx.x * (blockDim.x >> 2) + g;
    const int chunk = blockIdx.y;

    float4 vs[OO];
    #pragma unroll
    for (int o = 0; o < OO; ++o)
        vs[o] = *reinterpret_cast<const float4*>(vsum + (size_t)bl * ROW + o * OL + q * 4);

    float4 sp[OO];
    #pragma unroll
    for (int o = 0; o < OO; ++o) sp[o] = make_float4(0.f, 0.f, 0.f, 0.f);

    const unsigned short* ub = u + ((size_t)bl * NIN + (size_t)chunk * NPER) * ROW;
    for (int nn = 0; nn < NPER; ++nn) {
        const unsigned short* un = ub + (size_t)nn * ROW;
        ushx4 raw[OO];
        #pragma unroll
        for (int o = 0; o < OO; ++o)
            raw[o] = *reinterpret_cast<const ushx4*>(un + o * OL + q * 4);

        float bij[OO];
        #pragma unroll
        for (int o = 0; o < OO; ++o) {
            float d = bf2f(raw[o][0]) * vs[o].x;
            d = fmaf(bf2f(raw[o][1]), vs[o].y, d);
            d = fmaf(bf2f(raw[o][2]), vs[o].z, d);
            d = fmaf(bf2f(raw[o][3]), vs[o].w, d);
            d += __shfl_xor(d, 1, 4);
            d += __shfl_xor(d, 2, 4);
            bij[o] = d;
        }
        float m = bij[0];
        #pragma unroll
        for (int o = 1; o < OO; ++o) m = fmaxf(m, bij[o]);
        float e[OO], se = 0.f;
        #pragma unroll
        for (int o = 0; o < OO; ++o) { e[o] = __expf(bij[o] - m); se += e[o]; }
        const float r = 1.f / se;
        #pragma unroll
        for (int o = 0; o < OO; ++o) {
            const float c = e[o] * r;
            sp[o].x = fmaf(c, bf2f(raw[o][0]), sp[o].x);
            sp[o].y = fmaf(c, bf2f(raw[o][1]), sp[o].y);
            sp[o].z = fmaf(c, bf2f(raw[o][2]), sp[o].z);
            sp[o].w = fmaf(c, bf2f(raw[o][3]), sp[o].w);
        }
    }
    float* pp = partial + ((size_t)bl * NCH + chunk) * ROW + q * 4;
    #pragma unroll
    for (int o = 0; o < OO; ++o)
        *reinterpret_cast<float4*>(pp + o * OL) = sp[o];
}

// K5: sum partials over chunks + bias, squash; optional prevAdd (v running sum).
__global__ __launch_bounds__(192) void caps_reduce_squash(
    const float* __restrict__ partial, const float* __restrict__ bias,
    const float* __restrict__ prevAdd, float* __restrict__ out)
{
    const int t = threadIdx.x;
    if (t >= ROW) return;
    const int bl = blockIdx.x;

    float s0 = bias[t], s1 = 0.f, s2 = 0.f, s3 = 0.f;
    const float* p = partial + (size_t)bl * NCH * ROW + t;
    for (int ch = 0; ch < NCH; ch += 4) {
        s0 += p[(size_t)(ch + 0) * ROW];
        s1 += p[(size_t)(ch + 1) * ROW];
        s2 += p[(size_t)(ch + 2) * ROW];
        s3 += p[(size_t)(ch + 3) * ROW];
    }
    float s = (s0 + s1) + (s2 + s3);

    float d = s * s;
    d += __shfl_xor(d, 1, 16);
    d += __shfl_xor(d, 2, 16);
    d += __shfl_xor(d, 4, 16);
    d += __shfl_xor(d, 8, 16);
    const float f = d / ((1.f + d) * sqrtf(d + EPSQ));
    float v = f * s;
    if (prevAdd) v += prevAdd[(size_t)bl * ROW + t];
    out[(size_t)bl * ROW + t] = v;
}

extern "C" void kernel_launch(void* const* d_in, const int* in_sizes, int n_in,
                              void* d_out, int out_size, void* d_ws, size_t ws_size,
                              hipStream_t stream) {
    const float* x    = (const float*)d_in[0]; // (B, NIN, 8, 1)
    const float* w    = (const float*)d_in[1]; // (1, NIN, O, 8, 16)
    const float* bias = (const float*)d_in[2]; // (1, 1, O, 16, 1)
    float* out = (float*)d_out;                // (B, 1, O, 16, 1)

    unsigned short* u  = (unsigned short*)d_ws;                      // BB*NIN*ROW bf16
    float* partial = (float*)((char*)d_ws + (size_t)BB * NIN * ROW * 2);
    float* v0  = partial + (size_t)BB * NCH * ROW;
    float* vsb = v0 + (size_t)BB * ROW;

    const dim3 bgrid(NIN / 16, BB / 8);
    const dim3 g4(BB / 64, NCH);

    caps_build<<<bgrid, 320, 0, stream>>>(x, w, u);
    caps_iter0<<<BB, 256, 0, stream>>>(u, bias, v0);
    caps_iter<<<g4, 256, 0, stream>>>(u, v0, partial);
    caps_reduce_squash<<<BB, 192, 0, stream>>>(partial, bias, v0, vsb);
    caps_iter<<<g4, 256, 0, stream>>>(u, vsb, partial);
    caps_reduce_squash<<<BB, 192, 0, stream>>>(partial, bias, nullptr, out);
}

// Round 6
// 92.359 us; speedup vs baseline: 1.3783x; 1.1124x over previous
//
#include <hip/hip_runtime.h>
#include <hip/hip_bf16.h>

#define BB   256
#define NIN  1152
#define OO   10
#define IL   8
#define OL   16
#define ROW  (OO*OL)      // 160
#define EPSQ 1e-7f

typedef unsigned short ushx8 __attribute__((ext_vector_type(8)));
typedef unsigned short ushx4 __attribute__((ext_vector_type(4)));

__device__ __forceinline__ float bf2f(unsigned short h) {
    unsigned u = ((unsigned)h) << 16;
    return __builtin_bit_cast(float, u);
}

// K1: build u_hat[b][n][o*16+k] in bf16, 16B stores.
// Block 320 = 16 n-groups x 20 octet-lanes (o, k8). Grid (NIN/16, BB/32).
// Each thread loops 32 b's; w (64 floats) MUST stay register-resident:
// __launch_bounds__(320, 1) lifts the VGPR cap (round-5 showed 52 VGPR ->
// w was re-loaded from L2 every iteration = 1.5 GB L2 traffic = the 42 us).
__global__ __launch_bounds__(320, 1) void caps_build(
    const float* __restrict__ x, const float* __restrict__ w,
    unsigned short* __restrict__ u)
{
    const int t  = threadIdx.x;
    const int nl = t / 20;             // 0..15
    const int s  = t - nl * 20;        // 0..19
    const int o  = s >> 1;
    const int k8 = s & 1;
    const int n  = blockIdx.x * 16 + nl;
    const int b0 = blockIdx.y * 32;

    // w[n, o, i, k8*8 .. +7], i = 0..7 -> 64 register-resident coeffs
    const float* wb = w + (size_t)n * (OO * IL * OL) + (o * IL) * OL + k8 * 8;
    float wr[IL][8];
    #pragma unroll
    for (int i = 0; i < IL; ++i) {
        const float4 wa = *reinterpret_cast<const float4*>(wb + i * OL);
        const float4 wc = *reinterpret_cast<const float4*>(wb + i * OL + 4);
        wr[i][0] = wa.x; wr[i][1] = wa.y; wr[i][2] = wa.z; wr[i][3] = wa.w;
        wr[i][4] = wc.x; wr[i][5] = wc.y; wr[i][6] = wc.z; wr[i][7] = wc.w;
    }

    const float4* xb = reinterpret_cast<const float4*>(x + ((size_t)b0 * NIN + n) * IL);
    unsigned short* ub = u + ((size_t)b0 * NIN + n) * ROW + o * OL + k8 * 8;

    #pragma unroll 4
    for (int bl = 0; bl < 32; ++bl) {
        const float4 xa = xb[(size_t)bl * (NIN * 2)];
        const float4 xc = xb[(size_t)bl * (NIN * 2) + 1];
        const float xv[IL] = {xa.x, xa.y, xa.z, xa.w, xc.x, xc.y, xc.z, xc.w};

        float uv[8];
        #pragma unroll
        for (int j = 0; j < 8; ++j) {
            float acc = wr[0][j] * xv[0];
            #pragma unroll
            for (int i = 1; i < IL; ++i) acc = fmaf(wr[i][j], xv[i], acc);
            uv[j] = acc;
        }

        union { ushx8 v; __hip_bfloat162 h[4]; } pk;
        #pragma unroll
        for (int j = 0; j < 4; ++j)
            pk.h[j] = __float22bfloat162_rn(make_float2(uv[2 * j], uv[2 * j + 1]));
        *reinterpret_cast<ushx8*>(ub + (size_t)bl * ((size_t)NIN * ROW)) = pk.v;
    }
}

// K2: fused routing pass. One block per b (512 threads = 128 4-lane groups).
// Group g handles n = g + m*128, m=0..8. Computes s = scale*sum_n(c*u) + bias
// in-block (wave butterfly + LDS cross-wave), applies squash, writes v.
// vsum == null -> uniform c (iter0, scale=0.1); else c = softmax(u . vsum).
__global__ __launch_bounds__(512) void caps_route(
    const unsigned short* __restrict__ u, const float* __restrict__ vsum,
    const float* __restrict__ bias, const float* __restrict__ prevAdd,
    float* __restrict__ outv, float scale)
{
    __shared__ float lds[8][ROW];
    const int t = threadIdx.x;
    const int q = t & 3;
    const int g = t >> 2;              // 0..127
    const int b = blockIdx.x;
    const int wv = t >> 6;             // wave 0..7

    float4 sp[OO];
    #pragma unroll
    for (int o = 0; o < OO; ++o) sp[o] = make_float4(0.f, 0.f, 0.f, 0.f);

    const unsigned short* ub = u + (size_t)b * NIN * ROW + (q << 2);

    if (vsum == nullptr) {
        for (int m = 0; m < 9; ++m) {
            const unsigned short* un = ub + (size_t)(g + (m << 7)) * ROW;
            #pragma unroll
            for (int o = 0; o < OO; ++o) {
                const ushx4 raw = *reinterpret_cast<const ushx4*>(un + o * OL);
                sp[o].x += bf2f(raw[0]);
                sp[o].y += bf2f(raw[1]);
                sp[o].z += bf2f(raw[2]);
                sp[o].w += bf2f(raw[3]);
            }
        }
    } else {
        float4 vs[OO];
        #pragma unroll
        for (int o = 0; o < OO; ++o)
            vs[o] = *reinterpret_cast<const float4*>(vsum + (size_t)b * ROW + o * OL + q * 4);

        for (int m = 0; m < 9; ++m) {
            const unsigned short* un = ub + (size_t)(g + (m << 7)) * ROW;
            ushx4 raw[OO];
            #pragma unroll
            for (int o = 0; o < OO; ++o)
                raw[o] = *reinterpret_cast<const ushx4*>(un + o * OL);

            float bij[OO];
            #pragma unroll
            for (int o = 0; o < OO; ++o) {
                float d = bf2f(raw[o][0]) * vs[o].x;
                d = fmaf(bf2f(raw[o][1]), vs[o].y, d);
                d = fmaf(bf2f(raw[o][2]), vs[o].z, d);
                d = fmaf(bf2f(raw[o][3]), vs[o].w, d);
                d += __shfl_xor(d, 1, 4);
                d += __shfl_xor(d, 2, 4);
                bij[o] = d;
            }
            float mx = bij[0];
            #pragma unroll
            for (int o = 1; o < OO; ++o) mx = fmaxf(mx, bij[o]);
            float e[OO], se = 0.f;
            #pragma unroll
            for (int o = 0; o < OO; ++o) { e[o] = __expf(bij[o] - mx); se += e[o]; }
            const float r = 1.f / se;
            #pragma unroll
            for (int o = 0; o < OO; ++o) {
                const float c = e[o] * r;
                sp[o].x = fmaf(c, bf2f(raw[o][0]), sp[o].x);
                sp[o].y = fmaf(c, bf2f(raw[o][1]), sp[o].y);
                sp[o].z = fmaf(c, bf2f(raw[o][2]), sp[o].z);
                sp[o].w = fmaf(c, bf2f(raw[o][3]), sp[o].w);
            }
        }
    }

    // butterfly all-reduce over the 16 groups of each wave (masks 4..32
    // preserve q = lane&3)
    #pragma unroll
    for (int o = 0; o < OO; ++o) {
        #pragma unroll
        for (int msk = 4; msk <= 32; msk <<= 1) {
            sp[o].x += __shfl_xor(sp[o].x, msk);
            sp[o].y += __shfl_xor(sp[o].y, msk);
            sp[o].z += __shfl_xor(sp[o].z, msk);
            sp[o].w += __shfl_xor(sp[o].w, msk);
        }
    }
    if ((t & 63) < 4) {
        #pragma unroll
        for (int o = 0; o < OO; ++o) {
            lds[wv][o * OL + q * 4 + 0] = sp[o].x;
            lds[wv][o * OL + q * 4 + 1] = sp[o].y;
            lds[wv][o * OL + q * 4 + 2] = sp[o].z;
            lds[wv][o * OL + q * 4 + 3] = sp[o].w;
        }
    }
    __syncthreads();

    if (t < ROW) {
        float ssum = 0.f;
        #pragma unroll
        for (int wvi = 0; wvi < 8; ++wvi) ssum += lds[wvi][t];
        const float sv = scale * ssum + bias[t];

        float d = sv * sv;
        d += __shfl_xor(d, 1, 16);
        d += __shfl_xor(d, 2, 16);
        d += __shfl_xor(d, 4, 16);
        d += __shfl_xor(d, 8, 16);
        const float f = d / ((1.f + d) * sqrtf(d + EPSQ));
        float v = f * sv;
        if (prevAdd) v += prevAdd[(size_t)b * ROW + t];
        outv[(size_t)b * ROW + t] = v;
    }
}

extern "C" void kernel_launch(void* const* d_in, const int* in_sizes, int n_in,
                              void* d_out, int out_size, void* d_ws, size_t ws_size,
                              hipStream_t stream) {
    const float* x    = (const float*)d_in[0]; // (B, NIN, 8, 1)
    const float* w    = (const float*)d_in[1]; // (1, NIN, O, 8, 16)
    const float* bias = (const float*)d_in[2]; // (1, 1, O, 16, 1)
    float* out = (float*)d_out;                // (B, 1, O, 16, 1)

    unsigned short* u = (unsigned short*)d_ws;                 // BB*NIN*ROW bf16
    float* v0  = (float*)((char*)d_ws + (size_t)BB * NIN * ROW * 2);
    float* vsb = v0 + (size_t)BB * ROW;

    caps_build<<<dim3(NIN / 16, BB / 32), 320, 0, stream>>>(x, w, u);
    // iter0: uniform c -> v0
    caps_route<<<BB, 512, 0, stream>>>(u, nullptr, bias, nullptr, v0, 0.1f);
    // iter1: c = softmax(u.v0) -> vsb = v1 + v0
    caps_route<<<BB, 512, 0, stream>>>(u, v0, bias, v0, vsb, 1.0f);
    // iter2: c = softmax(u.(v0+v1)) -> out
    caps_route<<<BB, 512, 0, stream>>>(u, vsb, bias, nullptr, out, 1.0f);
}

// Round 7
// 87.582 us; speedup vs baseline: 1.4534x; 1.0545x over previous
//
#include <hip/hip_runtime.h>
#include <hip/hip_bf16.h>

#define BB   256
#define NIN  1152
#define OO   10
#define IL   8
#define OL   16
#define ROW  (OO*OL)      // 160
#define EPSQ 1e-7f
#define NT   8            // n-tile per build block
#define BT   32           // b-tile per build block

typedef unsigned short ushx8 __attribute__((ext_vector_type(8)));
typedef unsigned short ushx4 __attribute__((ext_vector_type(4)));

__device__ __forceinline__ float bf2f(unsigned short h) {
    unsigned u = ((unsigned)h) << 16;
    return __builtin_bit_cast(float, u);
}

// K1: build u_hat[b][n][o*16+k] in bf16.
// Block 160 = 8 n-groups x 20 (o,k8) lanes. Grid (NIN/8, BB/32).
// w slice staged in LDS ONCE per block (compiler was re-reading w from L2
// every iteration -> 1.5 GB L2 traffic = the 42 us; LDS makes reuse explicit).
// Bank swizzle: i' = i ^ (o&1) spreads the 10 o-lanes per (nl,k8) that would
// otherwise alias to the same 4 banks -> uniform 8 dwords/bank.
// Inner loop does 2 b's per w-read (halves LDS traffic; regs stay < 64).
__global__ __launch_bounds__(160) void caps_build(
    const float* __restrict__ x, const float* __restrict__ w,
    unsigned short* __restrict__ u)
{
    __shared__ float4 wl4[NT][321];     // 320 float4 per n + 1 pad (row = 1284 floats)
    __shared__ float4 xl4[BT * 16];     // [bl][nl*2+h]
    const int t  = threadIdx.x;
    const int n0 = blockIdx.x * NT;
    const int b0 = blockIdx.y * BT;

    // stage w (swizzled), coalesced global reads
    const float4* wg = reinterpret_cast<const float4*>(w) + (size_t)n0 * 320;
    for (int j = t; j < NT * 320; j += 160) {
        const int row = j / 320;
        const int lin = j - row * 320;
        const int o   = lin >> 5;
        const int rem = lin & 31;
        const int i   = rem >> 2;
        const int kh  = rem & 3;
        const int ip  = i ^ (o & 1);
        wl4[row][(o << 5) | (ip << 2) | kh] = wg[j];
    }
    // stage x (linear, coalesced)
    const float4* xg = reinterpret_cast<const float4*>(x);
    for (int j = t; j < BT * 16; j += 160) {
        const int bl = j >> 4;
        const int r  = j & 15;
        xl4[j] = xg[((size_t)(b0 + bl) * NIN + n0) * 2 + r];
    }
    __syncthreads();

    const int nl = t / 20;
    const int s  = t - nl * 20;
    const int o  = s >> 1;
    const int k8 = s & 1;
    const int p  = o & 1;
    const float4* wbase = &wl4[nl][(o << 5) | (k8 << 1)];
    const float4* xbase = &xl4[nl * 2];
    unsigned short* ub = u + ((size_t)b0 * NIN + n0 + nl) * ROW + o * OL + k8 * 8;
    const size_t ustride = (size_t)NIN * ROW;

    for (int bl = 0; bl < BT; bl += 2) {
        const float4 xa0 = xbase[bl * 16];
        const float4 xa1 = xbase[bl * 16 + 1];
        const float4 xb0 = xbase[bl * 16 + 16];
        const float4 xb1 = xbase[bl * 16 + 17];
        const float xv0[IL] = {xa0.x, xa0.y, xa0.z, xa0.w, xa1.x, xa1.y, xa1.z, xa1.w};
        const float xv1[IL] = {xb0.x, xb0.y, xb0.z, xb0.w, xb1.x, xb1.y, xb1.z, xb1.w};

        float a0[8] = {0,0,0,0,0,0,0,0};
        float a1[8] = {0,0,0,0,0,0,0,0};
        #pragma unroll
        for (int i = 0; i < IL; ++i) {
            const float4 wlo = wbase[(i ^ p) << 2];
            const float4 whi = wbase[((i ^ p) << 2) | 1];
            const float wv[8] = {wlo.x, wlo.y, wlo.z, wlo.w, whi.x, whi.y, whi.z, whi.w};
            #pragma unroll
            for (int j = 0; j < 8; ++j) {
                a0[j] = fmaf(wv[j], xv0[i], a0[j]);
                a1[j] = fmaf(wv[j], xv1[i], a1[j]);
            }
        }
        union { ushx8 v; __hip_bfloat162 h[4]; } p0, p1;
        #pragma unroll
        for (int j = 0; j < 4; ++j) {
            p0.h[j] = __float22bfloat162_rn(make_float2(a0[2*j], a0[2*j+1]));
            p1.h[j] = __float22bfloat162_rn(make_float2(a1[2*j], a1[2*j+1]));
        }
        *reinterpret_cast<ushx8*>(ub + (size_t)bl * ustride)       = p0.v;
        *reinterpret_cast<ushx8*>(ub + (size_t)(bl + 1) * ustride) = p1.v;
    }
}

// K2: all 3 routing iterations fused, one block per b (768 thr = 192 4-lane
// groups, 6 n-steps). v passes between iterations via LDS; only final v hits
// global. vbuf holds v0 after iter0 and v0+v1 after iter1 (linearized b_ij).
__global__ __launch_bounds__(768) void caps_route3(
    const unsigned short* __restrict__ u, const float* __restrict__ bias,
    float* __restrict__ outv)
{
    __shared__ float lds[12][ROW];
    __shared__ float vbuf[ROW];
    const int t  = threadIdx.x;
    const int q  = t & 3;
    const int g  = t >> 2;     // 0..191
    const int wv = t >> 6;     // 0..11
    const int b  = blockIdx.x;
    const unsigned short* ub = u + (size_t)b * NIN * ROW + (q << 2);

    float bsv = 0.f;
    if (t < ROW) bsv = bias[t];
    float vprev = 0.f;

    float4 sp[OO];

    #pragma unroll
    for (int iter = 0; iter < 3; ++iter) {
        #pragma unroll
        for (int o = 0; o < OO; ++o) sp[o] = make_float4(0.f, 0.f, 0.f, 0.f);

        if (iter == 0) {
            for (int m = 0; m < 6; ++m) {
                const unsigned short* un = ub + (size_t)(g + m * 192) * ROW;
                #pragma unroll
                for (int o = 0; o < OO; ++o) {
                    const ushx4 raw = *reinterpret_cast<const ushx4*>(un + o * OL);
                    sp[o].x += bf2f(raw[0]);
                    sp[o].y += bf2f(raw[1]);
                    sp[o].z += bf2f(raw[2]);
                    sp[o].w += bf2f(raw[3]);
                }
            }
        } else {
            float4 vs[OO];
            #pragma unroll
            for (int o = 0; o < OO; ++o)
                vs[o] = *reinterpret_cast<const float4*>(&vbuf[o * OL + (q << 2)]);

            for (int m = 0; m < 6; ++m) {
                const unsigned short* un = ub + (size_t)(g + m * 192) * ROW;
                ushx4 raw[OO];
                #pragma unroll
                for (int o = 0; o < OO; ++o)
                    raw[o] = *reinterpret_cast<const ushx4*>(un + o * OL);

                float bij[OO];
                #pragma unroll
                for (int o = 0; o < OO; ++o) {
                    float d = bf2f(raw[o][0]) * vs[o].x;
                    d = fmaf(bf2f(raw[o][1]), vs[o].y, d);
                    d = fmaf(bf2f(raw[o][2]), vs[o].z, d);
                    d = fmaf(bf2f(raw[o][3]), vs[o].w, d);
                    d += __shfl_xor(d, 1, 4);
                    d += __shfl_xor(d, 2, 4);
                    bij[o] = d;
                }
                float mx = bij[0];
                #pragma unroll
                for (int o = 1; o < OO; ++o) mx = fmaxf(mx, bij[o]);
                float e[OO], se = 0.f;
                #pragma unroll
                for (int o = 0; o < OO; ++o) { e[o] = __expf(bij[o] - mx); se += e[o]; }
                const float r = 1.f / se;
                #pragma unroll
                for (int o = 0; o < OO; ++o) {
                    const float c = e[o] * r;
                    sp[o].x = fmaf(c, bf2f(raw[o][0]), sp[o].x);
                    sp[o].y = fmaf(c, bf2f(raw[o][1]), sp[o].y);
                    sp[o].z = fmaf(c, bf2f(raw[o][2]), sp[o].z);
                    sp[o].w = fmaf(c, bf2f(raw[o][3]), sp[o].w);
                }
            }
        }

        // butterfly over the 16 groups of each wave (masks preserve q)
        #pragma unroll
        for (int o = 0; o < OO; ++o) {
            #pragma unroll
            for (int msk = 4; msk <= 32; msk <<= 1) {
                sp[o].x += __shfl_xor(sp[o].x, msk);
                sp[o].y += __shfl_xor(sp[o].y, msk);
                sp[o].z += __shfl_xor(sp[o].z, msk);
                sp[o].w += __shfl_xor(sp[o].w, msk);
            }
        }
        if ((t & 63) < 4) {
            #pragma unroll
            for (int o = 0; o < OO; ++o) {
                lds[wv][o * OL + q * 4 + 0] = sp[o].x;
                lds[wv][o * OL + q * 4 + 1] = sp[o].y;
                lds[wv][o * OL + q * 4 + 2] = sp[o].z;
                lds[wv][o * OL + q * 4 + 3] = sp[o].w;
            }
        }
        __syncthreads();

        if (t < ROW) {
            float ssum = 0.f;
            #pragma unroll
            for (int wvi = 0; wvi < 12; ++wvi) ssum += lds[wvi][t];
            const float sv = (iter == 0 ? 0.1f : 1.0f) * ssum + bsv;

            float d = sv * sv;
            d += __shfl_xor(d, 1, 16);
            d += __shfl_xor(d, 2, 16);
            d += __shfl_xor(d, 4, 16);
            d += __shfl_xor(d, 8, 16);
            const float f = d / ((1.f + d) * sqrtf(d + EPSQ));
            const float v = f * sv;

            if (iter == 0) { vbuf[t] = v; vprev = v; }
            else if (iter == 1) { vbuf[t] = v + vprev; }
            else { outv[(size_t)b * ROW + t] = v; }
        }
        __syncthreads();
    }
}

extern "C" void kernel_launch(void* const* d_in, const int* in_sizes, int n_in,
                              void* d_out, int out_size, void* d_ws, size_t ws_size,
                              hipStream_t stream) {
    const float* x    = (const float*)d_in[0]; // (B, NIN, 8, 1)
    const float* w    = (const float*)d_in[1]; // (1, NIN, O, 8, 16)
    const float* bias = (const float*)d_in[2]; // (1, 1, O, 16, 1)
    float* out = (float*)d_out;                // (B, 1, O, 16, 1)

    unsigned short* u = (unsigned short*)d_ws; // BB*NIN*ROW bf16 = 94.4 MB

    caps_build<<<dim3(NIN / NT, BB / BT), 160, 0, stream>>>(x, w, u);
    caps_route3<<<BB, 768, 0, stream>>>(u, bias, out);
}

// Round 8
// 85.565 us; speedup vs baseline: 1.4877x; 1.0236x over previous
//
#include <hip/hip_runtime.h>
#include <hip/hip_bf16.h>

#define BB   256
#define NIN  1152
#define OO   10
#define IL   8
#define OL   16
#define ROW  (OO*OL)      // 160
#define EPSQ 1e-7f
#define NT   8            // n-tile per build block
#define BT   32           // b-tile per build block

typedef unsigned short ushx8 __attribute__((ext_vector_type(8)));
typedef unsigned short ushx4 __attribute__((ext_vector_type(4)));

__device__ __forceinline__ float bf2f(unsigned short h) {
    unsigned u = ((unsigned)h) << 16;
    return __builtin_bit_cast(float, u);
}

// K1: build u_hat[b][n][o*16+k] in bf16.
// Block 160 = 8 n-groups x 20 (o,k8) lanes. Grid (NIN/8, BB/32).
// w staged in LDS once (o-parity swizzle -> conflict-free); inner loop does
// 4 b's per w-read (round 7 did 2; w-LDS traffic halves 655->327 KB/block).
__global__ __launch_bounds__(160) void caps_build(
    const float* __restrict__ x, const float* __restrict__ w,
    unsigned short* __restrict__ u)
{
    __shared__ float4 wl4[NT][321];     // 320 float4 per n + 1 pad
    __shared__ float4 xl4[BT * 16];     // [bl][nl*2+h]
    const int t  = threadIdx.x;
    const int n0 = blockIdx.x * NT;
    const int b0 = blockIdx.y * BT;

    // stage w (swizzled), coalesced global reads
    const float4* wg = reinterpret_cast<const float4*>(w) + (size_t)n0 * 320;
    for (int j = t; j < NT * 320; j += 160) {
        const int row = j / 320;
        const int lin = j - row * 320;
        const int o   = lin >> 5;
        const int rem = lin & 31;
        const int i   = rem >> 2;
        const int kh  = rem & 3;
        const int ip  = i ^ (o & 1);
        wl4[row][(o << 5) | (ip << 2) | kh] = wg[j];
    }
    // stage x (linear, coalesced)
    const float4* xg = reinterpret_cast<const float4*>(x);
    for (int j = t; j < BT * 16; j += 160) {
        const int bl = j >> 4;
        const int r  = j & 15;
        xl4[j] = xg[((size_t)(b0 + bl) * NIN + n0) * 2 + r];
    }
    __syncthreads();

    const int nl = t / 20;
    const int s  = t - nl * 20;
    const int o  = s >> 1;
    const int k8 = s & 1;
    const int p  = o & 1;
    const float4* wbase = &wl4[nl][(o << 5) | (k8 << 1)];
    const float4* xbase = &xl4[nl * 2];
    unsigned short* ub = u + ((size_t)b0 * NIN + n0 + nl) * ROW + o * OL + k8 * 8;
    const size_t ustride = (size_t)NIN * ROW;

    for (int bl = 0; bl < BT; bl += 4) {
        float xv[4][IL];
        #pragma unroll
        for (int bb = 0; bb < 4; ++bb) {
            const float4 x0 = xbase[(bl + bb) * 16];
            const float4 x1 = xbase[(bl + bb) * 16 + 1];
            xv[bb][0] = x0.x; xv[bb][1] = x0.y; xv[bb][2] = x0.z; xv[bb][3] = x0.w;
            xv[bb][4] = x1.x; xv[bb][5] = x1.y; xv[bb][6] = x1.z; xv[bb][7] = x1.w;
        }

        float acc[4][8];
        #pragma unroll
        for (int bb = 0; bb < 4; ++bb)
            #pragma unroll
            for (int j = 0; j < 8; ++j) acc[bb][j] = 0.f;

        #pragma unroll
        for (int i = 0; i < IL; ++i) {
            const float4 wlo = wbase[(i ^ p) << 2];
            const float4 whi = wbase[((i ^ p) << 2) | 1];
            const float wv[8] = {wlo.x, wlo.y, wlo.z, wlo.w, whi.x, whi.y, whi.z, whi.w};
            #pragma unroll
            for (int bb = 0; bb < 4; ++bb)
                #pragma unroll
                for (int j = 0; j < 8; ++j)
                    acc[bb][j] = fmaf(wv[j], xv[bb][i], acc[bb][j]);
        }

        #pragma unroll
        for (int bb = 0; bb < 4; ++bb) {
            union { ushx8 v; __hip_bfloat162 h[4]; } pk;
            #pragma unroll
            for (int j = 0; j < 4; ++j)
                pk.h[j] = __float22bfloat162_rn(make_float2(acc[bb][2*j], acc[bb][2*j+1]));
            *reinterpret_cast<ushx8*>(ub + (size_t)(bl + bb) * ustride) = pk.v;
        }
    }
}

// K2: all 3 routing iterations fused, one block per b (768 thr = 192 4-lane
// groups, 6 n-steps). Lane q of a group owns row chunks {q+4j} (16B = 8 bf16
// of one o): lanes 0/1 = even o (halves 0/1), lanes 2/3 = odd o. Full-k dot
// via in-lane 8-FMA + shfl_xor(1); cross-parity dots via shfl_xor(2).
// 16B loads halve the VMEM instruction count vs round 7 (the 55us limiter).
__global__ __launch_bounds__(768) void caps_route3(
    const unsigned short* __restrict__ u, const float* __restrict__ bias,
    float* __restrict__ outv)
{
    __shared__ float lds[12][ROW];
    __shared__ float vbuf[ROW];
    const int t  = threadIdx.x;
    const int q  = t & 3;
    const int g  = t >> 2;     // 0..191
    const int wv = t >> 6;     // 0..11
    const int b  = blockIdx.x;
    const unsigned short* ub = u + (size_t)b * NIN * ROW;

    float bsv = 0.f;
    if (t < ROW) bsv = bias[t];
    float vprev = 0.f;

    #pragma unroll
    for (int iter = 0; iter < 3; ++iter) {
        float sp[5][8];
        #pragma unroll
        for (int j = 0; j < 5; ++j)
            #pragma unroll
            for (int e = 0; e < 8; ++e) sp[j][e] = 0.f;

        if (iter == 0) {
            for (int m = 0; m < 6; ++m) {
                const unsigned short* un = ub + (size_t)(g + m * 192) * ROW;
                #pragma unroll
                for (int j = 0; j < 5; ++j) {
                    const ushx8 raw = *reinterpret_cast<const ushx8*>(un + (q + 4 * j) * 8);
                    #pragma unroll
                    for (int e = 0; e < 8; ++e) sp[j][e] += bf2f(raw[e]);
                }
            }
        } else {
            float vs[5][8];
            #pragma unroll
            for (int j = 0; j < 5; ++j) {
                #pragma unroll
                for (int e = 0; e < 8; ++e) vs[j][e] = vbuf[(q + 4 * j) * 8 + e];
            }

            for (int m = 0; m < 6; ++m) {
                const unsigned short* un = ub + (size_t)(g + m * 192) * ROW;
                float uf[5][8];
                #pragma unroll
                for (int j = 0; j < 5; ++j) {
                    const ushx8 raw = *reinterpret_cast<const ushx8*>(un + (q + 4 * j) * 8);
                    #pragma unroll
                    for (int e = 0; e < 8; ++e) uf[j][e] = bf2f(raw[e]);
                }

                // own-parity dots (half-k), combine halves, then swap parity
                float d[5], dd[5];
                #pragma unroll
                for (int j = 0; j < 5; ++j) {
                    float acc = uf[j][0] * vs[j][0];
                    #pragma unroll
                    for (int e = 1; e < 8; ++e) acc = fmaf(uf[j][e], vs[j][e], acc);
                    acc += __shfl_xor(acc, 1, 4);   // h=0 + h=1 -> full 16-k dot
                    d[j] = acc;
                }
                #pragma unroll
                for (int j = 0; j < 5; ++j) dd[j] = __shfl_xor(d[j], 2, 4);

                float mx = fmaxf(d[0], dd[0]);
                #pragma unroll
                for (int j = 1; j < 5; ++j) mx = fmaxf(mx, fmaxf(d[j], dd[j]));
                float se = 0.f, e_[5];
                #pragma unroll
                for (int j = 0; j < 5; ++j) {
                    e_[j] = __expf(d[j] - mx);
                    se += e_[j] + __expf(dd[j] - mx);
                }
                const float r = 1.f / se;
                #pragma unroll
                for (int j = 0; j < 5; ++j) {
                    const float c = e_[j] * r;
                    #pragma unroll
                    for (int e = 0; e < 8; ++e)
                        sp[j][e] = fmaf(c, uf[j][e], sp[j][e]);
                }
            }
        }

        // butterfly over the 16 groups of each wave (masks preserve q)
        #pragma unroll
        for (int j = 0; j < 5; ++j)
            #pragma unroll
            for (int e = 0; e < 8; ++e) {
                #pragma unroll
                for (int msk = 4; msk <= 32; msk <<= 1)
                    sp[j][e] += __shfl_xor(sp[j][e], msk);
            }
        if ((t & 63) < 4) {
            #pragma unroll
            for (int j = 0; j < 5; ++j)
                #pragma unroll
                for (int e = 0; e < 8; ++e)
                    lds[wv][(q + 4 * j) * 8 + e] = sp[j][e];
        }
        __syncthreads();

        if (t < ROW) {
            float ssum = 0.f;
            #pragma unroll
            for (int wvi = 0; wvi < 12; ++wvi) ssum += lds[wvi][t];
            const float sv = (iter == 0 ? 0.1f : 1.0f) * ssum + bsv;

            float dq = sv * sv;
            dq += __shfl_xor(dq, 1, 16);
            dq += __shfl_xor(dq, 2, 16);
            dq += __shfl_xor(dq, 4, 16);
            dq += __shfl_xor(dq, 8, 16);
            const float f = dq / ((1.f + dq) * sqrtf(dq + EPSQ));
            const float v = f * sv;

            if (iter == 0) { vbuf[t] = v; vprev = v; }
            else if (iter == 1) { vbuf[t] = v + vprev; }
            else { outv[(size_t)b * ROW + t] = v; }
        }
        __syncthreads();
    }
}

extern "C" void kernel_launch(void* const* d_in, const int* in_sizes, int n_in,
                              void* d_out, int out_size, void* d_ws, size_t ws_size,
                              hipStream_t stream) {
    const float* x    = (const float*)d_in[0]; // (B, NIN, 8, 1)
    const float* w    = (const float*)d_in[1]; // (1, NIN, O, 8, 16)
    const float* bias = (const float*)d_in[2]; // (1, 1, O, 16, 1)
    float* out = (float*)d_out;                // (B, 1, O, 16, 1)

    unsigned short* u = (unsigned short*)d_ws; // BB*NIN*ROW bf16 = 94.4 MB

    caps_build<<<dim3(NIN / NT, BB / BT), 160, 0, stream>>>(x, w, u);
    caps_route3<<<BB, 768, 0, stream>>>(u, bias, out);
}